// Round 14
// baseline (336.911 us; speedup 1.0000x reference)
//
#include <hip/hip_runtime.h>
#include <cstdint>
#include <cstddef>

#define B_   4
#define S_   2047
#define T_   2048
#define D_   256
#define H_   8
#define DK_  32
#define DFF_ 512
#define L_   2

typedef short          s8v  __attribute__((ext_vector_type(8)));
typedef float          f4v  __attribute__((ext_vector_type(4)));
typedef unsigned short u8v  __attribute__((ext_vector_type(8)));
typedef unsigned int   u2v  __attribute__((ext_vector_type(2)));
typedef unsigned int   uint32;

union U8 { u8v v; unsigned short e[8]; };

__device__ __forceinline__ float bf2f(unsigned short h) {
    unsigned int u = ((unsigned int)h) << 16;
    float f; __builtin_memcpy(&f, &u, 4); return f;
}
__device__ __forceinline__ unsigned short f2bf(float f) {
    unsigned int u; __builtin_memcpy(&u, &f, 4);
    u += 0x7fffu + ((u >> 16) & 1u);        // RNE
    return (unsigned short)(u >> 16);
}
__device__ __forceinline__ uint32 pack_bf2(float lo, float hi) {
    uint32 a, b;
    __builtin_memcpy(&a, &lo, 4); __builtin_memcpy(&b, &hi, 4);
    a += 0x8000u; b += 0x8000u;
    return __builtin_amdgcn_perm(b, a, 0x07060302);  // hi16(b)<<16 | hi16(a)
}

// log2(e)/sqrt(32): Q pre-scale so softmax runs in base-2 (exp2 = bare v_exp_f32)
#define QSCALE2 0.25503485951542068f

// ------- prep: embed (blocks 0..1023) + ALL weight transposes (1024..2047) --
__global__ __launch_bounds__(256) void prep_k(
    const float* __restrict__ emb, const int* __restrict__ toks,
    const float* __restrict__ tokE, const float* __restrict__ pe,
    unsigned short* __restrict__ X,
    const float* __restrict__ Wq, const float* __restrict__ Wk,
    const float* __restrict__ Wv, const float* __restrict__ Wo,
    const float* __restrict__ W1, const float* __restrict__ W2,
    unsigned short* __restrict__ WqkvT, unsigned short* __restrict__ WoT,
    unsigned short* __restrict__ W1T, unsigned short* __restrict__ W2T)
{
    __shared__ float tile[32][33];
    if (blockIdx.x < 1024) {
        int idx = blockIdx.x * 256 + threadIdx.x;      // B*T*32
        int d8 = (idx & 31) * 8;
        int t  = (idx >> 5) & (T_ - 1);
        int b  = idx >> 16;
        const float* src = (t == 0) ? (emb + b * D_)
                                    : (tokE + (size_t)toks[b * S_ + t - 1] * D_);
        const float* p = pe + (size_t)t * D_ + d8;
        U8 o;
#pragma unroll
        for (int j = 0; j < 8; ++j) o.e[j] = f2bf(src[d8 + j] + p[j]);
        *(u8v*)(X + (size_t)(b * T_ + t) * D_ + d8) = o.v;
        return;
    }
    int idx = blockIdx.x - 1024;
    const float* src; unsigned short* dst; int R, C, tr, tc;
    if (idx < 512) {
        int w = idx >> 7, rem = idx & 127, l = rem >> 6, t = rem & 63;
        tr = t >> 3; tc = t & 7; R = 256; C = 256;
        src = (w == 0 ? Wq : w == 1 ? Wk : w == 2 ? Wv : Wo) + (size_t)l * 65536;
        dst = (w < 3) ? WqkvT + (size_t)l * 196608 + (size_t)w * 65536
                      : WoT + (size_t)l * 65536;
    } else if (idx < 768) {
        int rem = idx - 512, l = rem >> 7, t = rem & 127;
        tr = t >> 4; tc = t & 15; R = 256; C = 512;
        src = W1 + (size_t)l * 131072; dst = W1T + (size_t)l * 131072;
    } else {
        int rem = idx - 768, l = rem >> 7, t = rem & 127;
        tr = t >> 3; tc = t & 7; R = 512; C = 256;
        src = W2 + (size_t)l * 131072; dst = W2T + (size_t)l * 131072;
    }
    int x = threadIdx.x & 31, y = threadIdx.x >> 5;
    int r0 = tr * 32, c0 = tc * 32;
#pragma unroll
    for (int i = 0; i < 32; i += 8) tile[y + i][x] = src[(size_t)(r0 + y + i) * C + c0 + x];
    __syncthreads();
#pragma unroll
    for (int i = 0; i < 32; i += 8)
        dst[(size_t)(c0 + y + i) * R + r0 + x] = f2bf(tile[x][y + i]);
}

// ---- GEMM 64x64 tile, BK=64, reg-prefetch.  C = A[M,K] @ WT[N,K]^T ---------
// mode 0: QKV. blockIdx.y in [0,12): sub=y>>2 (0:Q scaled,1:K,2:V transposed)
__global__ __launch_bounds__(256) void gemm64_k(
    const unsigned short* __restrict__ A, const unsigned short* __restrict__ WT,
    const float* __restrict__ bias,
    unsigned short* __restrict__ oq, unsigned short* __restrict__ ok,
    unsigned short* __restrict__ ov, unsigned short* __restrict__ out,
    int K, int Ntot, int mode)
{
    __shared__ unsigned short At[64 * 72];
    __shared__ unsigned short Wt[64 * 72];
    const int tid = threadIdx.x;
    const int wave = tid >> 6, lane = tid & 63, l15 = lane & 15, quad = lane >> 4;
    const int m0 = blockIdx.x * 64, n0g = blockIdx.y * 64;

    f4v acc[4];
#pragma unroll
    for (int i = 0; i < 4; ++i) acc[i] = (f4v){0.f, 0.f, 0.f, 0.f};

    const int arow = tid >> 2, acg = (tid & 3) * 16;
    const unsigned short* ag = A + (size_t)(m0 + arow) * K + acg;
    const unsigned short* wg = WT + (size_t)(n0g + arow) * K + acg;
    u8v a0 = *(const u8v*)ag, a1 = *(const u8v*)(ag + 8);
    u8v w0 = *(const u8v*)wg, w1 = *(const u8v*)(wg + 8);

    const int niter = K >> 6;
    for (int kk = 0; kk < niter; ++kk) {
        *(u8v*)&At[arow * 72 + acg] = a0; *(u8v*)&At[arow * 72 + acg + 8] = a1;
        *(u8v*)&Wt[arow * 72 + acg] = w0; *(u8v*)&Wt[arow * 72 + acg + 8] = w1;
        __syncthreads();
        if (kk + 1 < niter) {
            int o = (kk + 1) * 64;
            a0 = *(const u8v*)(ag + o); a1 = *(const u8v*)(ag + o + 8);
            w0 = *(const u8v*)(wg + o); w1 = *(const u8v*)(wg + o + 8);
        }
#pragma unroll
        for (int ks = 0; ks < 2; ++ks) {
            s8v aF = *(const s8v*)&At[(wave * 16 + l15) * 72 + ks * 32 + quad * 8];
#pragma unroll
            for (int nt = 0; nt < 4; ++nt) {
                s8v wF = *(const s8v*)&Wt[(nt * 16 + l15) * 72 + ks * 32 + quad * 8];
                acc[nt] = __builtin_amdgcn_mfma_f32_16x16x32_bf16(aF, wF, acc[nt], 0, 0, 0);
            }
        }
        __syncthreads();
    }

    const int b = m0 >> 11, t0 = m0 & (T_ - 1);
    if (mode == 0) {
        int sub = blockIdx.y >> 2;
        int cb  = (blockIdx.y & 3) * 64;
        if (sub < 2) {
            unsigned short* dst = sub ? ok : oq;
            float sc = sub ? 1.f : QSCALE2;
#pragma unroll
            for (int nt = 0; nt < 4; ++nt) {
                int c = cb + nt * 16 + l15, hh = c >> 5, dk = c & 31;
#pragma unroll
                for (int r = 0; r < 4; ++r) {
                    int t = t0 + wave * 16 + quad * 4 + r;
                    dst[((size_t)(b * H_ + hh) * T_ + t) * DK_ + dk] = f2bf(acc[nt][r] * sc);
                }
            }
        } else {
            unsigned short* Vb = At;   // reuse: [64 cols][72]
#pragma unroll
            for (int nt = 0; nt < 4; ++nt) {
                int base = (nt * 16 + l15) * 72 + wave * 16 + quad * 4;
                *(uint32*)&Vb[base]     = pack_bf2(acc[nt][0], acc[nt][1]);
                *(uint32*)&Vb[base + 2] = pack_bf2(acc[nt][2], acc[nt][3]);
            }
            __syncthreads();
            int c = tid >> 2, chunk = tid & 3;
            int cg = cb + c, hh = cg >> 5, dk = cg & 31;
            unsigned short* dst = ov + ((size_t)(b * H_ + hh) * DK_ + dk) * T_ + t0 + chunk * 16;
            u8v v0 = *(u8v*)&Vb[c * 72 + chunk * 16];
            u8v v1 = *(u8v*)&Vb[c * 72 + chunk * 16 + 8];
            *(u8v*)dst = v0; *(u8v*)(dst + 8) = v1;
        }
    } else {
#pragma unroll
        for (int nt = 0; nt < 4; ++nt) {
            int c = n0g + nt * 16 + l15;
            float bv = bias[c];
#pragma unroll
            for (int r = 0; r < 4; ++r) {
                float v = acc[nt][r] + bv;
                v = v > 0.f ? v : 0.f;
                out[(size_t)(m0 + wave * 16 + quad * 4 + r) * Ntot + c] = f2bf(v);
            }
        }
    }
}

// ---- fused tail, 16-WAVE blocks (R7-proven): 4 waves/SIMD to hide per-step
// L2 staging latency.  Each wave owns a 32-col slice.
__global__ __launch_bounds__(1024, 4) void tail32_k(
    const unsigned short* __restrict__ AO,
    const unsigned short* __restrict__ WoTl, const float* __restrict__ bo,
    const unsigned short* __restrict__ Xres,
    const float* __restrict__ g1, const float* __restrict__ be1,
    const unsigned short* __restrict__ W1Tl, const float* __restrict__ b1,
    const unsigned short* __restrict__ W2Tl, const float* __restrict__ b2,
    const float* __restrict__ g2, const float* __restrict__ be2,
    unsigned short* __restrict__ Xout, float* __restrict__ fout, int last)
{
    __shared__ unsigned short Wt[256 * 72];     // 36864 B
    __shared__ unsigned short As[32 * 72];      //  4608 B
    __shared__ unsigned short X1s[32 * 264];    // 16896 B
    __shared__ unsigned short Hs[32 * 520];     // 33280 B
    __shared__ float LNsc[512];                 //  2048 B   (sum | sumsq at +256)

    const int tid = threadIdx.x;
    const int wave = tid >> 6, lane = tid & 63, l15 = lane & 15, quad = lane >> 4;
    const int wr = wave >> 3, wc = wave & 7;
    const int m0 = blockIdx.x * 32;
    const int rbase = wr * 16 + quad * 4;

    const int wrow = tid >> 2, wcol = (tid & 3) * 16;   // W: 256 rows x 64K, 32B/thread
    const int arow = tid >> 3, acol = (tid & 7) * 8;    // A: 32 rows x 64K (tid<256)

    f4v acc[2];
    u8v w0, w1, a0 = {0,0,0,0,0,0,0,0};

    const unsigned short* wgo = WoTl + (size_t)wrow * 256 + wcol;
    const unsigned short* wg1 = W1Tl + (size_t)wrow * 256 + wcol;
    const unsigned short* wg1b = W1Tl + (size_t)(256 + wrow) * 256 + wcol;
    const unsigned short* wg2 = W2Tl + (size_t)wrow * 512 + wcol;
    const unsigned short* ag  = AO + (size_t)(m0 + arow) * 256 + acol;

#define LDW(p, o) { w0 = *(const u8v*)((p)+(o)); w1 = *(const u8v*)((p)+(o)+8); }
#define STW { *(u8v*)&Wt[wrow*72+wcol] = w0; *(u8v*)&Wt[wrow*72+wcol+8] = w1; }

    // ================= U1: AO @ WoT^T =================
#pragma unroll
    for (int i = 0; i < 2; ++i) acc[i] = (f4v){0.f, 0.f, 0.f, 0.f};
    LDW(wgo, 0);
    if (tid < 256) a0 = *(const u8v*)ag;
    for (int kk = 0; kk < 4; ++kk) {
        STW;
        if (tid < 256) *(u8v*)&As[arow * 72 + acol] = a0;
        __syncthreads();
        if (kk < 3) {
            LDW(wgo, (kk + 1) * 64);
            if (tid < 256) a0 = *(const u8v*)(ag + (kk + 1) * 64);
        } else {
            LDW(wg1, 0);
        }
#pragma unroll
        for (int ks = 0; ks < 2; ++ks) {
            s8v aF = *(const s8v*)&As[(wr * 16 + l15) * 72 + ks * 32 + quad * 8];
#pragma unroll
            for (int nt = 0; nt < 2; ++nt) {
                s8v wF = *(const s8v*)&Wt[(wc * 32 + nt * 16 + l15) * 72 + ks * 32 + quad * 8];
                acc[nt] = __builtin_amdgcn_mfma_f32_16x16x32_bf16(aF, wF, acc[nt], 0, 0, 0);
            }
        }
        __syncthreads();
    }
    // ---- epilogue U1: bias + resid(global X) + LN1 -> X1s ----
    {
        float ps[4] = {0,0,0,0}, pq[4] = {0,0,0,0};
#pragma unroll
        for (int nt = 0; nt < 2; ++nt) {
            int c = wc * 32 + nt * 16 + l15;
            float bv = bo[c];
#pragma unroll
            for (int r = 0; r < 4; ++r) {
                float v = acc[nt][r] + bv + bf2f(Xres[(size_t)(m0 + rbase + r) * D_ + c]);
                acc[nt][r] = v; ps[r] += v; pq[r] += v * v;
            }
        }
#pragma unroll
        for (int r = 0; r < 4; ++r) {
            float s = ps[r], q = pq[r];
            s += __shfl_xor(s, 1); q += __shfl_xor(q, 1);
            s += __shfl_xor(s, 2); q += __shfl_xor(q, 2);
            s += __shfl_xor(s, 4); q += __shfl_xor(q, 4);
            s += __shfl_xor(s, 8); q += __shfl_xor(q, 8);
            if (l15 == 0) { LNsc[(rbase + r) * 8 + wc] = s; LNsc[256 + (rbase + r) * 8 + wc] = q; }
        }
        __syncthreads();
#pragma unroll
        for (int r = 0; r < 4; ++r) {
            int row = rbase + r;
            float s = 0.f, q = 0.f;
#pragma unroll
            for (int j = 0; j < 8; ++j) { s += LNsc[row * 8 + j]; q += LNsc[256 + row * 8 + j]; }
            float m = s * (1.f / 256.f);
            float rs = rsqrtf(q * (1.f / 256.f) - m * m + 1e-5f);
#pragma unroll
            for (int nt = 0; nt < 2; ++nt) {
                int c = wc * 32 + nt * 16 + l15;
                X1s[row * 264 + c] = f2bf((acc[nt][r] - m) * rs * g1[c] + be1[c]);
            }
        }
        __syncthreads();
    }

    // ================= FF1-a: H[:,0:256] = relu(X1 @ W1T[0:256]^T + b1) =====
#pragma unroll
    for (int i = 0; i < 2; ++i) acc[i] = (f4v){0.f, 0.f, 0.f, 0.f};
    for (int kk = 0; kk < 4; ++kk) {
        STW;
        __syncthreads();
        if (kk < 3) LDW(wg1, (kk + 1) * 64) else LDW(wg1b, 0);
#pragma unroll
        for (int ks = 0; ks < 2; ++ks) {
            s8v aF = *(const s8v*)&X1s[(wr * 16 + l15) * 264 + kk * 64 + ks * 32 + quad * 8];
#pragma unroll
            for (int nt = 0; nt < 2; ++nt) {
                s8v wF = *(const s8v*)&Wt[(wc * 32 + nt * 16 + l15) * 72 + ks * 32 + quad * 8];
                acc[nt] = __builtin_amdgcn_mfma_f32_16x16x32_bf16(aF, wF, acc[nt], 0, 0, 0);
            }
        }
        __syncthreads();
    }
#pragma unroll
    for (int nt = 0; nt < 2; ++nt) {
        int c = wc * 32 + nt * 16 + l15;
        float bv = b1[c];
#pragma unroll
        for (int r = 0; r < 4; ++r) {
            float v = acc[nt][r] + bv; v = v > 0.f ? v : 0.f;
            Hs[(rbase + r) * 520 + c] = f2bf(v);
        }
    }

    // ================= FF1-b: H[:,256:512] =================
#pragma unroll
    for (int i = 0; i < 2; ++i) acc[i] = (f4v){0.f, 0.f, 0.f, 0.f};
    for (int kk = 0; kk < 4; ++kk) {
        STW;
        __syncthreads();
        if (kk < 3) LDW(wg1b, (kk + 1) * 64) else LDW(wg2, 0);
#pragma unroll
        for (int ks = 0; ks < 2; ++ks) {
            s8v aF = *(const s8v*)&X1s[(wr * 16 + l15) * 264 + kk * 64 + ks * 32 + quad * 8];
#pragma unroll
            for (int nt = 0; nt < 2; ++nt) {
                s8v wF = *(const s8v*)&Wt[(wc * 32 + nt * 16 + l15) * 72 + ks * 32 + quad * 8];
                acc[nt] = __builtin_amdgcn_mfma_f32_16x16x32_bf16(aF, wF, acc[nt], 0, 0, 0);
            }
        }
        __syncthreads();
    }
#pragma unroll
    for (int nt = 0; nt < 2; ++nt) {
        int c = wc * 32 + nt * 16 + l15;
        float bv = b1[256 + c];
#pragma unroll
        for (int r = 0; r < 4; ++r) {
            float v = acc[nt][r] + bv; v = v > 0.f ? v : 0.f;
            Hs[(rbase + r) * 520 + 256 + c] = f2bf(v);
        }
    }

    // ================= U2: H @ W2T^T =================
#pragma unroll
    for (int i = 0; i < 2; ++i) acc[i] = (f4v){0.f, 0.f, 0.f, 0.f};
    for (int kk = 0; kk < 8; ++kk) {
        STW;
        __syncthreads();                        // also publishes Hs on kk==0
        if (kk < 7) LDW(wg2, (kk + 1) * 64);
#pragma unroll
        for (int ks = 0; ks < 2; ++ks) {
            s8v aF = *(const s8v*)&Hs[(wr * 16 + l15) * 520 + kk * 64 + ks * 32 + quad * 8];
#pragma unroll
            for (int nt = 0; nt < 2; ++nt) {
                s8v wF = *(const s8v*)&Wt[(wc * 32 + nt * 16 + l15) * 72 + ks * 32 + quad * 8];
                acc[nt] = __builtin_amdgcn_mfma_f32_16x16x32_bf16(aF, wF, acc[nt], 0, 0, 0);
            }
        }
        __syncthreads();
    }
    // ---- epilogue U2: bias + resid(X1s) + LN2 -> Xout / f32 out ----
    {
        float ps[4] = {0,0,0,0}, pq[4] = {0,0,0,0};
#pragma unroll
        for (int nt = 0; nt < 2; ++nt) {
            int c = wc * 32 + nt * 16 + l15;
            float bv = b2[c];
#pragma unroll
            for (int r = 0; r < 4; ++r) {
                float v = acc[nt][r] + bv + bf2f(X1s[(rbase + r) * 264 + c]);
                acc[nt][r] = v; ps[r] += v; pq[r] += v * v;
            }
        }
#pragma unroll
        for (int r = 0; r < 4; ++r) {
            float s = ps[r], q = pq[r];
            s += __shfl_xor(s, 1); q += __shfl_xor(q, 1);
            s += __shfl_xor(s, 2); q += __shfl_xor(q, 2);
            s += __shfl_xor(s, 4); q += __shfl_xor(q, 4);
            s += __shfl_xor(s, 8); q += __shfl_xor(q, 8);
            if (l15 == 0) { LNsc[(rbase + r) * 8 + wc] = s; LNsc[256 + (rbase + r) * 8 + wc] = q; }
        }
        __syncthreads();
#pragma unroll
        for (int r = 0; r < 4; ++r) {
            int row = rbase + r;
            float s = 0.f, q = 0.f;
#pragma unroll
            for (int j = 0; j < 8; ++j) { s += LNsc[row * 8 + j]; q += LNsc[256 + row * 8 + j]; }
            float m = s * (1.f / 256.f);
            float rs = rsqrtf(q * (1.f / 256.f) - m * m + 1e-5f);
#pragma unroll
            for (int nt = 0; nt < 2; ++nt) {
                int c = wc * 32 + nt * 16 + l15;
                float val = (acc[nt][r] - m) * rs * g2[c] + be2[c];
                if (!last) {
                    Xout[(size_t)(m0 + row) * D_ + c] = f2bf(val);
                } else {
                    int gr = m0 + row;
                    int t = gr & (T_ - 1), bb = gr >> 11;
                    if (t) fout[((size_t)bb * S_ + t - 1) * D_ + c] = val;
                }
            }
        }
    }
#undef LDW
#undef STW
}

// ---- flash attention, BARRIER-FREE: K/V read directly from L2 as MFMA
// fragments (K+V = 256 KB/head, fully L2-resident; both layouts give 16B-
// contiguous fragments, so LDS staging was a pure L2->LDS->reg copy — guide
// Common-mistake #7 / m169: dropping it was +26% there).  Cascade:
//  * zero __syncthreads in the k-loop (Ps is wave-private)
//  * LDS 74.7 -> 34.8 KB, VGPR 52 <= 64  ->  launch_bounds(512,8) = 4
//    blocks/CU = 32 waves/CU (full occupancy, was 16)
//  * each wave runs exactly its own nkt tiles: zero intra-block idle, and
//    per-block total work is uniform (4*nkt(x)+4*nkt(31-x) = 68 for all x)
// MFMA denominator (R11) retained.  Math byte-identical.
__global__ __launch_bounds__(512, 8) void attn_k(
    const unsigned short* __restrict__ Qh, const unsigned short* __restrict__ Kh,
    const unsigned short* __restrict__ VT, unsigned short* __restrict__ AO)
{
    __shared__ unsigned short Ps[8][16 * 136];   // per-wave P [query][key]

    const int tid = threadIdx.x, wave = tid >> 6, lane = tid & 63;
    const int l15 = lane & 15, quad = lane >> 4;
    const int grp = wave >> 2, wl = wave & 3;

    const int bid = blockIdx.x;                  // 0..511
    const int bh = bid >> 4;                     // 0..31
    const int x  = (bid < 256) ? (bid & 15) : 15 - (bid & 15);
    const int b = bh >> 3, h = bh & 7;
    const size_t hoff = (size_t)bh * T_ * DK_;
    unsigned short* Pw = &Ps[wave][0];

    const int qt = grp ? 31 - x : x;          // my wave-group's q-tile
    const int nkt = qt / 2 + 1;               // my causal k-tiles (128 keys each)

    // direct-from-global fragment base pointers (16B-contiguous per lane):
    // K fragment nt at tile kt: rows kt*128 + nt*16 + l15, dk cols quad*8..+8
    const unsigned short* kfp = Kh + hoff + (size_t)l15 * DK_ + quad * 8;
    // V fragments at tile kt, ks: row l15 (+16), cols kt*128 + ks*32 + quad*8
    const unsigned short* vfp = VT + ((size_t)bh * DK_ + l15) * T_ + quad * 8;

    const int q0w = qt * 64 + wl * 16;
    const s8v qB = *(const s8v*)(Qh + hoff + (size_t)(q0w + l15) * DK_ + quad * 8);
    f4v O0 = {0,0,0,0}, O1 = {0,0,0,0};
    f4v Lacc = {0,0,0,0};                     // row-sum accumulator (P @ ones)
    const short one_bf = (short)0x3F80;       // bf16 1.0
    const s8v vOne = { one_bf, one_bf, one_bf, one_bf,
                       one_bf, one_bf, one_bf, one_bf };

    for (int kt = 0; kt < nkt; ++kt) {
        const int k0 = kt * 128;
        f4v s[8];
        f4v zero = {0,0,0,0};
#pragma unroll
        for (int nt = 0; nt < 8; ++nt) {
            s8v kA = *(const s8v*)(kfp + (size_t)(k0 + nt * 16) * DK_);
            s[nt] = __builtin_amdgcn_mfma_f32_16x16x32_bf16(kA, qB, zero, 0, 0, 0);
        }
        if (kt == nkt - 1) {                  // diagonal tile: causal mask
            int query = q0w + l15;
#pragma unroll
            for (int nt = 0; nt < 8; ++nt)
#pragma unroll
                for (int r = 0; r < 4; ++r) {
                    int key = k0 + nt * 16 + quad * 4 + r;
                    if (key > query) s[nt][r] = -1e30f;
                }
        }
#pragma unroll
        for (int nt = 0; nt < 8; ++nt)
#pragma unroll
            for (int r = 0; r < 4; ++r)
                s[nt][r] = exp2f(s[nt][r]);   // masked -> exp2(-1e30)=0
#pragma unroll
        for (int nt = 0; nt < 8; ++nt) {
            u2v pw;
            pw.x = pack_bf2(s[nt][0], s[nt][1]);
            pw.y = pack_bf2(s[nt][2], s[nt][3]);
            *(u2v*)&Pw[l15 * 136 + nt * 16 + quad * 4] = pw;
        }
#pragma unroll
        for (int ks = 0; ks < 4; ++ks) {
            s8v aP = *(const s8v*)&Pw[l15 * 136 + ks * 32 + quad * 8];
            s8v v0 = *(const s8v*)(vfp + k0 + ks * 32);
            s8v v1 = *(const s8v*)(vfp + (size_t)16 * T_ + k0 + ks * 32);
            O0 = __builtin_amdgcn_mfma_f32_16x16x32_bf16(aP, v0, O0, 0, 0, 0);
            O1 = __builtin_amdgcn_mfma_f32_16x16x32_bf16(aP, v1, O1, 0, 0, 0);
            Lacc = __builtin_amdgcn_mfma_f32_16x16x32_bf16(aP, vOne, Lacc, 0, 0, 0);
        }
    }
#pragma unroll
    for (int r = 0; r < 4; ++r) {
        float linv = 1.f / Lacc[r];           // broadcast across l15 lanes
        int row = q0w + quad * 4 + r;
        size_t base = (size_t)(b * T_ + row) * D_ + h * DK_;
        AO[base + l15]      = f2bf(O0[r] * linv);
        AO[base + 16 + l15] = f2bf(O1[r] * linv);
    }
}

extern "C" void kernel_launch(void* const* d_in, const int* in_sizes, int n_in,
                              void* d_out, int out_size, void* d_ws, size_t ws_size,
                              hipStream_t stream)
{
    const float* emb  = (const float*)d_in[0];
    const int*   toks = (const int*)d_in[1];
    const float* tokE = (const float*)d_in[4];
    const float* pe   = (const float*)d_in[5];
    const float* Wq   = (const float*)d_in[6];
    const float* Wk   = (const float*)d_in[7];
    const float* Wv   = (const float*)d_in[8];
    const float* Wo   = (const float*)d_in[9];
    const float* bo   = (const float*)d_in[10];
    const float* g1   = (const float*)d_in[11];
    const float* be1  = (const float*)d_in[12];
    const float* W1   = (const float*)d_in[13];
    const float* b1   = (const float*)d_in[14];
    const float* W2   = (const float*)d_in[15];
    const float* b2   = (const float*)d_in[16];
    const float* g2   = (const float*)d_in[17];
    const float* be2  = (const float*)d_in[18];
    float* out = (float*)d_out;

    unsigned short* ws = (unsigned short*)d_ws;
    size_t off = 0;
    const size_t XSZ = (size_t)B_ * T_ * D_;
    unsigned short* Xa    = ws + off; off += XSZ;
    unsigned short* Xb    = ws + off; off += XSZ;   // unused (layout stability)
    unsigned short* Qh    = ws + off; off += XSZ;
    unsigned short* Kh    = ws + off; off += XSZ;
    unsigned short* VTb   = ws + off; off += XSZ;
    unsigned short* AOb   = ws + off; off += XSZ;
    unsigned short* Hb    = ws + off; off += (size_t)B_ * T_ * DFF_;  // unused
    unsigned short* WqkvT = ws + off; off += (size_t)L_ * 3 * D_ * D_;
    unsigned short* WoT   = ws + off; off += (size_t)L_ * D_ * D_;
    unsigned short* W1T   = ws + off; off += (size_t)L_ * D_ * DFF_;
    unsigned short* W2T   = ws + off; off += (size_t)L_ * DFF_ * D_;
    (void)ws_size; (void)in_sizes; (void)n_in; (void)out_size;
    (void)Xb; (void)Hb;

    prep_k<<<dim3(2048), 256, 0, stream>>>(emb, toks, tokE, pe, Xa,
                                           Wq, Wk, Wv, Wo, W1, W2,
                                           WqkvT, WoT, W1T, W2T);

    for (int l = 0; l < L_; ++l) {
        const unsigned short* wqkv = WqkvT + (size_t)l * 3 * D_ * D_;
        const unsigned short* wo   = WoT + (size_t)l * D_ * D_;
        const unsigned short* w1   = W1T + (size_t)l * D_ * DFF_;
        const unsigned short* w2   = W2T + (size_t)l * DFF_ * D_;
        const int last = (l == L_ - 1);

        gemm64_k<<<dim3(128, 12), 256, 0, stream>>>(Xa, wqkv, nullptr,
                                                    Qh, Kh, VTb, nullptr, D_, D_, 0);
        attn_k<<<dim3(512), 512, 0, stream>>>(Qh, Kh, VTb, AOb);
        tail32_k<<<dim3(256), 1024, 0, stream>>>(AOb, wo, bo + l * D_, Xa,
                                                 g1 + l * D_, be1 + l * D_,
                                                 w1, b1 + l * DFF_,
                                                 w2, b2 + l * D_,
                                                 g2 + l * D_, be2 + l * D_,
                                                 Xa, out, last);
    }
}

// Round 15
// 242.147 us; speedup vs baseline: 1.3914x; 1.3914x over previous
//
#include <hip/hip_runtime.h>
#include <cstdint>
#include <cstddef>

#define B_   4
#define S_   2047
#define T_   2048
#define D_   256
#define H_   8
#define DK_  32
#define DFF_ 512
#define L_   2

typedef short          s8v  __attribute__((ext_vector_type(8)));
typedef float          f4v  __attribute__((ext_vector_type(4)));
typedef unsigned short u8v  __attribute__((ext_vector_type(8)));
typedef unsigned int   u2v  __attribute__((ext_vector_type(2)));
typedef unsigned int   uint32;

union U8 { u8v v; unsigned short e[8]; };

__device__ __forceinline__ float bf2f(unsigned short h) {
    unsigned int u = ((unsigned int)h) << 16;
    float f; __builtin_memcpy(&f, &u, 4); return f;
}
__device__ __forceinline__ unsigned short f2bf(float f) {
    unsigned int u; __builtin_memcpy(&u, &f, 4);
    u += 0x7fffu + ((u >> 16) & 1u);        // RNE
    return (unsigned short)(u >> 16);
}
__device__ __forceinline__ uint32 pack_bf2(float lo, float hi) {
    uint32 a, b;
    __builtin_memcpy(&a, &lo, 4); __builtin_memcpy(&b, &hi, 4);
    a += 0x8000u; b += 0x8000u;
    return __builtin_amdgcn_perm(b, a, 0x07060302);  // hi16(b)<<16 | hi16(a)
}

// log2(e)/sqrt(32): Q pre-scale so softmax runs in base-2 (exp2 = bare v_exp_f32)
#define QSCALE2 0.25503485951542068f

// ------- prep: embed (blocks 0..1023) + ALL weight transposes (1024..2047) --
__global__ __launch_bounds__(256) void prep_k(
    const float* __restrict__ emb, const int* __restrict__ toks,
    const float* __restrict__ tokE, const float* __restrict__ pe,
    unsigned short* __restrict__ X,
    const float* __restrict__ Wq, const float* __restrict__ Wk,
    const float* __restrict__ Wv, const float* __restrict__ Wo,
    const float* __restrict__ W1, const float* __restrict__ W2,
    unsigned short* __restrict__ WqkvT, unsigned short* __restrict__ WoT,
    unsigned short* __restrict__ W1T, unsigned short* __restrict__ W2T)
{
    __shared__ float tile[32][33];
    if (blockIdx.x < 1024) {
        int idx = blockIdx.x * 256 + threadIdx.x;      // B*T*32
        int d8 = (idx & 31) * 8;
        int t  = (idx >> 5) & (T_ - 1);
        int b  = idx >> 16;
        const float* src = (t == 0) ? (emb + b * D_)
                                    : (tokE + (size_t)toks[b * S_ + t - 1] * D_);
        const float* p = pe + (size_t)t * D_ + d8;
        U8 o;
#pragma unroll
        for (int j = 0; j < 8; ++j) o.e[j] = f2bf(src[d8 + j] + p[j]);
        *(u8v*)(X + (size_t)(b * T_ + t) * D_ + d8) = o.v;
        return;
    }
    int idx = blockIdx.x - 1024;
    const float* src; unsigned short* dst; int R, C, tr, tc;
    if (idx < 512) {
        int w = idx >> 7, rem = idx & 127, l = rem >> 6, t = rem & 63;
        tr = t >> 3; tc = t & 7; R = 256; C = 256;
        src = (w == 0 ? Wq : w == 1 ? Wk : w == 2 ? Wv : Wo) + (size_t)l * 65536;
        dst = (w < 3) ? WqkvT + (size_t)l * 196608 + (size_t)w * 65536
                      : WoT + (size_t)l * 65536;
    } else if (idx < 768) {
        int rem = idx - 512, l = rem >> 7, t = rem & 127;
        tr = t >> 4; tc = t & 15; R = 256; C = 512;
        src = W1 + (size_t)l * 131072; dst = W1T + (size_t)l * 131072;
    } else {
        int rem = idx - 768, l = rem >> 7, t = rem & 127;
        tr = t >> 3; tc = t & 7; R = 512; C = 256;
        src = W2 + (size_t)l * 131072; dst = W2T + (size_t)l * 131072;
    }
    int x = threadIdx.x & 31, y = threadIdx.x >> 5;
    int r0 = tr * 32, c0 = tc * 32;
#pragma unroll
    for (int i = 0; i < 32; i += 8) tile[y + i][x] = src[(size_t)(r0 + y + i) * C + c0 + x];
    __syncthreads();
#pragma unroll
    for (int i = 0; i < 32; i += 8)
        dst[(size_t)(c0 + y + i) * R + r0 + x] = f2bf(tile[x][y + i]);
}

// ---- GEMM 64x64 tile, BK=64, reg-prefetch.  C = A[M,K] @ WT[N,K]^T ---------
// mode 0: QKV. blockIdx.y in [0,12): sub=y>>2 (0:Q scaled,1:K,2:V transposed)
__global__ __launch_bounds__(256) void gemm64_k(
    const unsigned short* __restrict__ A, const unsigned short* __restrict__ WT,
    const float* __restrict__ bias,
    unsigned short* __restrict__ oq, unsigned short* __restrict__ ok,
    unsigned short* __restrict__ ov, unsigned short* __restrict__ out,
    int K, int Ntot, int mode)
{
    __shared__ unsigned short At[64 * 72];
    __shared__ unsigned short Wt[64 * 72];
    const int tid = threadIdx.x;
    const int wave = tid >> 6, lane = tid & 63, l15 = lane & 15, quad = lane >> 4;
    const int m0 = blockIdx.x * 64, n0g = blockIdx.y * 64;

    f4v acc[4];
#pragma unroll
    for (int i = 0; i < 4; ++i) acc[i] = (f4v){0.f, 0.f, 0.f, 0.f};

    const int arow = tid >> 2, acg = (tid & 3) * 16;
    const unsigned short* ag = A + (size_t)(m0 + arow) * K + acg;
    const unsigned short* wg = WT + (size_t)(n0g + arow) * K + acg;
    u8v a0 = *(const u8v*)ag, a1 = *(const u8v*)(ag + 8);
    u8v w0 = *(const u8v*)wg, w1 = *(const u8v*)(wg + 8);

    const int niter = K >> 6;
    for (int kk = 0; kk < niter; ++kk) {
        *(u8v*)&At[arow * 72 + acg] = a0; *(u8v*)&At[arow * 72 + acg + 8] = a1;
        *(u8v*)&Wt[arow * 72 + acg] = w0; *(u8v*)&Wt[arow * 72 + acg + 8] = w1;
        __syncthreads();
        if (kk + 1 < niter) {
            int o = (kk + 1) * 64;
            a0 = *(const u8v*)(ag + o); a1 = *(const u8v*)(ag + o + 8);
            w0 = *(const u8v*)(wg + o); w1 = *(const u8v*)(wg + o + 8);
        }
#pragma unroll
        for (int ks = 0; ks < 2; ++ks) {
            s8v aF = *(const s8v*)&At[(wave * 16 + l15) * 72 + ks * 32 + quad * 8];
#pragma unroll
            for (int nt = 0; nt < 4; ++nt) {
                s8v wF = *(const s8v*)&Wt[(nt * 16 + l15) * 72 + ks * 32 + quad * 8];
                acc[nt] = __builtin_amdgcn_mfma_f32_16x16x32_bf16(aF, wF, acc[nt], 0, 0, 0);
            }
        }
        __syncthreads();
    }

    const int b = m0 >> 11, t0 = m0 & (T_ - 1);
    if (mode == 0) {
        int sub = blockIdx.y >> 2;
        int cb  = (blockIdx.y & 3) * 64;
        if (sub < 2) {
            unsigned short* dst = sub ? ok : oq;
            float sc = sub ? 1.f : QSCALE2;
#pragma unroll
            for (int nt = 0; nt < 4; ++nt) {
                int c = cb + nt * 16 + l15, hh = c >> 5, dk = c & 31;
#pragma unroll
                for (int r = 0; r < 4; ++r) {
                    int t = t0 + wave * 16 + quad * 4 + r;
                    dst[((size_t)(b * H_ + hh) * T_ + t) * DK_ + dk] = f2bf(acc[nt][r] * sc);
                }
            }
        } else {
            unsigned short* Vb = At;   // reuse: [64 cols][72]
#pragma unroll
            for (int nt = 0; nt < 4; ++nt) {
                int base = (nt * 16 + l15) * 72 + wave * 16 + quad * 4;
                *(uint32*)&Vb[base]     = pack_bf2(acc[nt][0], acc[nt][1]);
                *(uint32*)&Vb[base + 2] = pack_bf2(acc[nt][2], acc[nt][3]);
            }
            __syncthreads();
            int c = tid >> 2, chunk = tid & 3;
            int cg = cb + c, hh = cg >> 5, dk = cg & 31;
            unsigned short* dst = ov + ((size_t)(b * H_ + hh) * DK_ + dk) * T_ + t0 + chunk * 16;
            u8v v0 = *(u8v*)&Vb[c * 72 + chunk * 16];
            u8v v1 = *(u8v*)&Vb[c * 72 + chunk * 16 + 8];
            *(u8v*)dst = v0; *(u8v*)(dst + 8) = v1;
        }
    } else {
#pragma unroll
        for (int nt = 0; nt < 4; ++nt) {
            int c = n0g + nt * 16 + l15;
            float bv = bias[c];
#pragma unroll
            for (int r = 0; r < 4; ++r) {
                float v = acc[nt][r] + bv;
                v = v > 0.f ? v : 0.f;
                out[(size_t)(m0 + wave * 16 + quad * 4 + r) * Ntot + c] = f2bf(v);
            }
        }
    }
}

// ---- fused tail, 16-WAVE blocks (R7-proven): 4 waves/SIMD to hide per-step
// L2 staging latency.  Each wave owns a 32-col slice.
__global__ __launch_bounds__(1024, 4) void tail32_k(
    const unsigned short* __restrict__ AO,
    const unsigned short* __restrict__ WoTl, const float* __restrict__ bo,
    const unsigned short* __restrict__ Xres,
    const float* __restrict__ g1, const float* __restrict__ be1,
    const unsigned short* __restrict__ W1Tl, const float* __restrict__ b1,
    const unsigned short* __restrict__ W2Tl, const float* __restrict__ b2,
    const float* __restrict__ g2, const float* __restrict__ be2,
    unsigned short* __restrict__ Xout, float* __restrict__ fout, int last)
{
    __shared__ unsigned short Wt[256 * 72];     // 36864 B
    __shared__ unsigned short As[32 * 72];      //  4608 B
    __shared__ unsigned short X1s[32 * 264];    // 16896 B
    __shared__ unsigned short Hs[32 * 520];     // 33280 B
    __shared__ float LNsc[512];                 //  2048 B   (sum | sumsq at +256)

    const int tid = threadIdx.x;
    const int wave = tid >> 6, lane = tid & 63, l15 = lane & 15, quad = lane >> 4;
    const int wr = wave >> 3, wc = wave & 7;
    const int m0 = blockIdx.x * 32;
    const int rbase = wr * 16 + quad * 4;

    const int wrow = tid >> 2, wcol = (tid & 3) * 16;   // W: 256 rows x 64K, 32B/thread
    const int arow = tid >> 3, acol = (tid & 7) * 8;    // A: 32 rows x 64K (tid<256)

    f4v acc[2];
    u8v w0, w1, a0 = {0,0,0,0,0,0,0,0};

    const unsigned short* wgo = WoTl + (size_t)wrow * 256 + wcol;
    const unsigned short* wg1 = W1Tl + (size_t)wrow * 256 + wcol;
    const unsigned short* wg1b = W1Tl + (size_t)(256 + wrow) * 256 + wcol;
    const unsigned short* wg2 = W2Tl + (size_t)wrow * 512 + wcol;
    const unsigned short* ag  = AO + (size_t)(m0 + arow) * 256 + acol;

#define LDW(p, o) { w0 = *(const u8v*)((p)+(o)); w1 = *(const u8v*)((p)+(o)+8); }
#define STW { *(u8v*)&Wt[wrow*72+wcol] = w0; *(u8v*)&Wt[wrow*72+wcol+8] = w1; }

    // ================= U1: AO @ WoT^T =================
#pragma unroll
    for (int i = 0; i < 2; ++i) acc[i] = (f4v){0.f, 0.f, 0.f, 0.f};
    LDW(wgo, 0);
    if (tid < 256) a0 = *(const u8v*)ag;
    for (int kk = 0; kk < 4; ++kk) {
        STW;
        if (tid < 256) *(u8v*)&As[arow * 72 + acol] = a0;
        __syncthreads();
        if (kk < 3) {
            LDW(wgo, (kk + 1) * 64);
            if (tid < 256) a0 = *(const u8v*)(ag + (kk + 1) * 64);
        } else {
            LDW(wg1, 0);
        }
#pragma unroll
        for (int ks = 0; ks < 2; ++ks) {
            s8v aF = *(const s8v*)&As[(wr * 16 + l15) * 72 + ks * 32 + quad * 8];
#pragma unroll
            for (int nt = 0; nt < 2; ++nt) {
                s8v wF = *(const s8v*)&Wt[(wc * 32 + nt * 16 + l15) * 72 + ks * 32 + quad * 8];
                acc[nt] = __builtin_amdgcn_mfma_f32_16x16x32_bf16(aF, wF, acc[nt], 0, 0, 0);
            }
        }
        __syncthreads();
    }
    // ---- epilogue U1: bias + resid(global X) + LN1 -> X1s ----
    {
        float ps[4] = {0,0,0,0}, pq[4] = {0,0,0,0};
#pragma unroll
        for (int nt = 0; nt < 2; ++nt) {
            int c = wc * 32 + nt * 16 + l15;
            float bv = bo[c];
#pragma unroll
            for (int r = 0; r < 4; ++r) {
                float v = acc[nt][r] + bv + bf2f(Xres[(size_t)(m0 + rbase + r) * D_ + c]);
                acc[nt][r] = v; ps[r] += v; pq[r] += v * v;
            }
        }
#pragma unroll
        for (int r = 0; r < 4; ++r) {
            float s = ps[r], q = pq[r];
            s += __shfl_xor(s, 1); q += __shfl_xor(q, 1);
            s += __shfl_xor(s, 2); q += __shfl_xor(q, 2);
            s += __shfl_xor(s, 4); q += __shfl_xor(q, 4);
            s += __shfl_xor(s, 8); q += __shfl_xor(q, 8);
            if (l15 == 0) { LNsc[(rbase + r) * 8 + wc] = s; LNsc[256 + (rbase + r) * 8 + wc] = q; }
        }
        __syncthreads();
#pragma unroll
        for (int r = 0; r < 4; ++r) {
            int row = rbase + r;
            float s = 0.f, q = 0.f;
#pragma unroll
            for (int j = 0; j < 8; ++j) { s += LNsc[row * 8 + j]; q += LNsc[256 + row * 8 + j]; }
            float m = s * (1.f / 256.f);
            float rs = rsqrtf(q * (1.f / 256.f) - m * m + 1e-5f);
#pragma unroll
            for (int nt = 0; nt < 2; ++nt) {
                int c = wc * 32 + nt * 16 + l15;
                X1s[row * 264 + c] = f2bf((acc[nt][r] - m) * rs * g1[c] + be1[c]);
            }
        }
        __syncthreads();
    }

    // ================= FF1-a: H[:,0:256] = relu(X1 @ W1T[0:256]^T + b1) =====
#pragma unroll
    for (int i = 0; i < 2; ++i) acc[i] = (f4v){0.f, 0.f, 0.f, 0.f};
    for (int kk = 0; kk < 4; ++kk) {
        STW;
        __syncthreads();
        if (kk < 3) LDW(wg1, (kk + 1) * 64) else LDW(wg1b, 0);
#pragma unroll
        for (int ks = 0; ks < 2; ++ks) {
            s8v aF = *(const s8v*)&X1s[(wr * 16 + l15) * 264 + kk * 64 + ks * 32 + quad * 8];
#pragma unroll
            for (int nt = 0; nt < 2; ++nt) {
                s8v wF = *(const s8v*)&Wt[(wc * 32 + nt * 16 + l15) * 72 + ks * 32 + quad * 8];
                acc[nt] = __builtin_amdgcn_mfma_f32_16x16x32_bf16(aF, wF, acc[nt], 0, 0, 0);
            }
        }
        __syncthreads();
    }
#pragma unroll
    for (int nt = 0; nt < 2; ++nt) {
        int c = wc * 32 + nt * 16 + l15;
        float bv = b1[c];
#pragma unroll
        for (int r = 0; r < 4; ++r) {
            float v = acc[nt][r] + bv; v = v > 0.f ? v : 0.f;
            Hs[(rbase + r) * 520 + c] = f2bf(v);
        }
    }

    // ================= FF1-b: H[:,256:512] =================
#pragma unroll
    for (int i = 0; i < 2; ++i) acc[i] = (f4v){0.f, 0.f, 0.f, 0.f};
    for (int kk = 0; kk < 4; ++kk) {
        STW;
        __syncthreads();
        if (kk < 3) LDW(wg1b, (kk + 1) * 64) else LDW(wg2, 0);
#pragma unroll
        for (int ks = 0; ks < 2; ++ks) {
            s8v aF = *(const s8v*)&X1s[(wr * 16 + l15) * 264 + kk * 64 + ks * 32 + quad * 8];
#pragma unroll
            for (int nt = 0; nt < 2; ++nt) {
                s8v wF = *(const s8v*)&Wt[(wc * 32 + nt * 16 + l15) * 72 + ks * 32 + quad * 8];
                acc[nt] = __builtin_amdgcn_mfma_f32_16x16x32_bf16(aF, wF, acc[nt], 0, 0, 0);
            }
        }
        __syncthreads();
    }
#pragma unroll
    for (int nt = 0; nt < 2; ++nt) {
        int c = wc * 32 + nt * 16 + l15;
        float bv = b1[256 + c];
#pragma unroll
        for (int r = 0; r < 4; ++r) {
            float v = acc[nt][r] + bv; v = v > 0.f ? v : 0.f;
            Hs[(rbase + r) * 520 + 256 + c] = f2bf(v);
        }
    }

    // ================= U2: H @ W2T^T =================
#pragma unroll
    for (int i = 0; i < 2; ++i) acc[i] = (f4v){0.f, 0.f, 0.f, 0.f};
    for (int kk = 0; kk < 8; ++kk) {
        STW;
        __syncthreads();                        // also publishes Hs on kk==0
        if (kk < 7) LDW(wg2, (kk + 1) * 64);
#pragma unroll
        for (int ks = 0; ks < 2; ++ks) {
            s8v aF = *(const s8v*)&Hs[(wr * 16 + l15) * 520 + kk * 64 + ks * 32 + quad * 8];
#pragma unroll
            for (int nt = 0; nt < 2; ++nt) {
                s8v wF = *(const s8v*)&Wt[(wc * 32 + nt * 16 + l15) * 72 + ks * 32 + quad * 8];
                acc[nt] = __builtin_amdgcn_mfma_f32_16x16x32_bf16(aF, wF, acc[nt], 0, 0, 0);
            }
        }
        __syncthreads();
    }
    // ---- epilogue U2: bias + resid(X1s) + LN2 -> Xout / f32 out ----
    {
        float ps[4] = {0,0,0,0}, pq[4] = {0,0,0,0};
#pragma unroll
        for (int nt = 0; nt < 2; ++nt) {
            int c = wc * 32 + nt * 16 + l15;
            float bv = b2[c];
#pragma unroll
            for (int r = 0; r < 4; ++r) {
                float v = acc[nt][r] + bv + bf2f(X1s[(rbase + r) * 264 + c]);
                acc[nt][r] = v; ps[r] += v; pq[r] += v * v;
            }
        }
#pragma unroll
        for (int r = 0; r < 4; ++r) {
            float s = ps[r], q = pq[r];
            s += __shfl_xor(s, 1); q += __shfl_xor(q, 1);
            s += __shfl_xor(s, 2); q += __shfl_xor(q, 2);
            s += __shfl_xor(s, 4); q += __shfl_xor(q, 4);
            s += __shfl_xor(s, 8); q += __shfl_xor(q, 8);
            if (l15 == 0) { LNsc[(rbase + r) * 8 + wc] = s; LNsc[256 + (rbase + r) * 8 + wc] = q; }
        }
        __syncthreads();
#pragma unroll
        for (int r = 0; r < 4; ++r) {
            int row = rbase + r;
            float s = 0.f, q = 0.f;
#pragma unroll
            for (int j = 0; j < 8; ++j) { s += LNsc[row * 8 + j]; q += LNsc[256 + row * 8 + j]; }
            float m = s * (1.f / 256.f);
            float rs = rsqrtf(q * (1.f / 256.f) - m * m + 1e-5f);
#pragma unroll
            for (int nt = 0; nt < 2; ++nt) {
                int c = wc * 32 + nt * 16 + l15;
                float val = (acc[nt][r] - m) * rs * g2[c] + be2[c];
                if (!last) {
                    Xout[(size_t)(m0 + row) * D_ + c] = f2bf(val);
                } else {
                    int gr = m0 + row;
                    int t = gr & (T_ - 1), bb = gr >> 11;
                    if (t) fout[((size_t)bb * S_ + t - 1) * D_ + c] = val;
                }
            }
        }
    }
#undef LDW
#undef STW
}

// ---- flash attention, 8-wave blocks (R8 structure) + MFMA-computed softmax
// denominator (verified best: 242.2us at R11 and R13).  LDS K/V staging is
// RETAINED deliberately: its value is cross-wave request amortization (one
// L2 load serves 8 waves) — R14's L2-direct variant removed it and regressed
// 39 -> 79us (8x L2 request amplification, latency-bound at 2 blocks/CU).
#define KTP 5120   // 128*40 u16 per K buffer
#define VTP 4864   // 32*152 u16 per V buffer
__global__ __launch_bounds__(512, 4) void attn_k(
    const unsigned short* __restrict__ Qh, const unsigned short* __restrict__ Kh,
    const unsigned short* __restrict__ VT, unsigned short* __restrict__ AO)
{
    __shared__ unsigned short Kt[2 * KTP];       // [buf][key][dk] pitch 40
    __shared__ unsigned short Vt[2 * VTP];       // [buf][dk][key] pitch 152
    __shared__ unsigned short Ps[8][16 * 136];   // per-wave P [query][key]

    const int tid = threadIdx.x, wave = tid >> 6, lane = tid & 63;
    const int l15 = lane & 15, quad = lane >> 4;
    const int grp = wave >> 2, wl = wave & 3;

    const int bid = blockIdx.x;                  // 0..511
    const int bh = bid >> 4;                     // 0..31
    const int x  = (bid < 256) ? (bid & 15) : 15 - (bid & 15);
    const int b = bh >> 3, h = bh & 7;
    const size_t hoff = (size_t)bh * T_ * DK_;
    unsigned short* Pw = &Ps[wave][0];

    const int qt = grp ? 31 - x : x;          // my group's q-tile
    const int nkt = qt / 2 + 1;               // my group's causal k-tiles
    const int nmax = (31 - x) / 2 + 1;        // block-wide k-tiles (grp1 >= grp0)

    const int krow = tid >> 2, kcol = (tid & 3) * 8;
    const int vdk = tid >> 4, vc = (tid & 15) * 8;
    const unsigned short* kgp = Kh + hoff + (size_t)krow * DK_ + kcol;
    const unsigned short* vgp = VT + ((size_t)bh * DK_ + vdk) * T_ + vc;

    u8v kr = *(const u8v*)kgp;
    u8v vr = *(const u8v*)vgp;

    const int q0w = qt * 64 + wl * 16;
    const s8v qB = *(const s8v*)(Qh + hoff + (size_t)(q0w + l15) * DK_ + quad * 8);
    f4v O0 = {0,0,0,0}, O1 = {0,0,0,0};
    f4v Lacc = {0,0,0,0};                     // row-sum accumulator (P @ ones)
    const short one_bf = (short)0x3F80;       // bf16 1.0
    const s8v vOne = { one_bf, one_bf, one_bf, one_bf,
                       one_bf, one_bf, one_bf, one_bf };

    for (int kt = 0; kt < nmax; ++kt) {
        unsigned short* Ktb = Kt + (kt & 1) * KTP;
        unsigned short* Vtb = Vt + (kt & 1) * VTP;
        *(u8v*)&Ktb[krow * 40 + kcol] = kr;
        *(u8v*)&Vtb[vdk * 152 + vc]   = vr;
        __syncthreads();    // single barrier/tile (dbuf)
        if (kt + 1 < nmax) {
            kr = *(const u8v*)(kgp + (size_t)(kt + 1) * 128 * DK_);
            vr = *(const u8v*)(vgp + (kt + 1) * 128);
        }
        if (kt < nkt) {
            const int k0 = kt * 128;
            f4v s[8];
            f4v zero = {0,0,0,0};
#pragma unroll
            for (int nt = 0; nt < 8; ++nt) {
                s8v kA = *(const s8v*)&Ktb[(nt * 16 + l15) * 40 + quad * 8];
                s[nt] = __builtin_amdgcn_mfma_f32_16x16x32_bf16(kA, qB, zero, 0, 0, 0);
            }
            if (kt == nkt - 1) {
                int query = q0w + l15;
#pragma unroll
                for (int nt = 0; nt < 8; ++nt)
#pragma unroll
                    for (int r = 0; r < 4; ++r) {
                        int key = k0 + nt * 16 + quad * 4 + r;
                        if (key > query) s[nt][r] = -1e30f;
                    }
            }
#pragma unroll
            for (int nt = 0; nt < 8; ++nt)
#pragma unroll
                for (int r = 0; r < 4; ++r)
                    s[nt][r] = exp2f(s[nt][r]);   // masked -> exp2(-1e30)=0
#pragma unroll
            for (int nt = 0; nt < 8; ++nt) {
                u2v pw;
                pw.x = pack_bf2(s[nt][0], s[nt][1]);
                pw.y = pack_bf2(s[nt][2], s[nt][3]);
                *(u2v*)&Pw[l15 * 136 + nt * 16 + quad * 4] = pw;
            }
#pragma unroll
            for (int ks = 0; ks < 4; ++ks) {
                s8v aP = *(const s8v*)&Pw[l15 * 136 + ks * 32 + quad * 8];
                s8v v0 = *(const s8v*)&Vtb[l15 * 152 + ks * 32 + quad * 8];
                s8v v1 = *(const s8v*)&Vtb[(16 + l15) * 152 + ks * 32 + quad * 8];
                O0 = __builtin_amdgcn_mfma_f32_16x16x32_bf16(aP, v0, O0, 0, 0, 0);
                O1 = __builtin_amdgcn_mfma_f32_16x16x32_bf16(aP, v1, O1, 0, 0, 0);
                Lacc = __builtin_amdgcn_mfma_f32_16x16x32_bf16(aP, vOne, Lacc, 0, 0, 0);
            }
            if (kt == nkt - 1) {
#pragma unroll
                for (int r = 0; r < 4; ++r) {
                    float linv = 1.f / Lacc[r];   // broadcast across l15 lanes
                    int row = q0w + quad * 4 + r;
                    size_t base = (size_t)(b * T_ + row) * D_ + h * DK_;
                    AO[base + l15]      = f2bf(O0[r] * linv);
                    AO[base + 16 + l15] = f2bf(O1[r] * linv);
                }
            }
        }
    }
}

extern "C" void kernel_launch(void* const* d_in, const int* in_sizes, int n_in,
                              void* d_out, int out_size, void* d_ws, size_t ws_size,
                              hipStream_t stream)
{
    const float* emb  = (const float*)d_in[0];
    const int*   toks = (const int*)d_in[1];
    const float* tokE = (const float*)d_in[4];
    const float* pe   = (const float*)d_in[5];
    const float* Wq   = (const float*)d_in[6];
    const float* Wk   = (const float*)d_in[7];
    const float* Wv   = (const float*)d_in[8];
    const float* Wo   = (const float*)d_in[9];
    const float* bo   = (const float*)d_in[10];
    const float* g1   = (const float*)d_in[11];
    const float* be1  = (const float*)d_in[12];
    const float* W1   = (const float*)d_in[13];
    const float* b1   = (const float*)d_in[14];
    const float* W2   = (const float*)d_in[15];
    const float* b2   = (const float*)d_in[16];
    const float* g2   = (const float*)d_in[17];
    const float* be2  = (const float*)d_in[18];
    float* out = (float*)d_out;

    unsigned short* ws = (unsigned short*)d_ws;
    size_t off = 0;
    const size_t XSZ = (size_t)B_ * T_ * D_;
    unsigned short* Xa    = ws + off; off += XSZ;
    unsigned short* Xb    = ws + off; off += XSZ;   // unused (layout stability)
    unsigned short* Qh    = ws + off; off += XSZ;
    unsigned short* Kh    = ws + off; off += XSZ;
    unsigned short* VTb   = ws + off; off += XSZ;
    unsigned short* AOb   = ws + off; off += XSZ;
    unsigned short* Hb    = ws + off; off += (size_t)B_ * T_ * DFF_;  // unused
    unsigned short* WqkvT = ws + off; off += (size_t)L_ * 3 * D_ * D_;
    unsigned short* WoT   = ws + off; off += (size_t)L_ * D_ * D_;
    unsigned short* W1T   = ws + off; off += (size_t)L_ * D_ * DFF_;
    unsigned short* W2T   = ws + off; off += (size_t)L_ * DFF_ * D_;
    (void)ws_size; (void)in_sizes; (void)n_in; (void)out_size;
    (void)Xb; (void)Hb;

    prep_k<<<dim3(2048), 256, 0, stream>>>(emb, toks, tokE, pe, Xa,
                                           Wq, Wk, Wv, Wo, W1, W2,
                                           WqkvT, WoT, W1T, W2T);

    for (int l = 0; l < L_; ++l) {
        const unsigned short* wqkv = WqkvT + (size_t)l * 3 * D_ * D_;
        const unsigned short* wo   = WoT + (size_t)l * D_ * D_;
        const unsigned short* w1   = W1T + (size_t)l * D_ * DFF_;
        const unsigned short* w2   = W2T + (size_t)l * DFF_ * D_;
        const int last = (l == L_ - 1);

        gemm64_k<<<dim3(128, 12), 256, 0, stream>>>(Xa, wqkv, nullptr,
                                                    Qh, Kh, VTb, nullptr, D_, D_, 0);
        attn_k<<<dim3(512), 512, 0, stream>>>(Qh, Kh, VTb, AOb);
        tail32_k<<<dim3(256), 1024, 0, stream>>>(AOb, wo, bo + l * D_, Xa,
                                                 g1 + l * D_, be1 + l * D_,
                                                 w1, b1 + l * DFF_,
                                                 w2, b2 + l * D_,
                                                 g2 + l * D_, be2 + l * D_,
                                                 Xa, out, last);
    }
}